// Round 2
// baseline (634.043 us; speedup 1.0000x reference)
//
#include <hip/hip_runtime.h>
#include <hip/hip_bf16.h>

// MultiHeadAttention: x(8,256,32,32) -> qkv proj -> global-softmax attention -> out proj.
// All GEMMs cast to one NT pattern: A(M,K) K-contig, B(N,K) K-contig, C(M,N) row-major.
//   g1: scaled_t[n,l,o] = (x_t[l,c] . w_in[o,c] + b_in[o]) * SCALE          (C rows=l cols=o)
//   g2: P[m,l] = exp(k_t[m,d] . q_t[l,d]); Z[nh] += sum                     (K=256)
//   g3: out_tt[n,m,h*256+d] = (P[m,l] . v2[d,l]) / Z[nh]                    (K=1024)
//   g4: out[n,c,m] = w_out[c,a] . out_tt[m,a] + b_out[c]                    (K=2048)
// Global softmax: att ~ N(0,0.17^2), |att|max ~ 1, so exp() without max-subtraction is safe.

typedef __bf16 bf16x8 __attribute__((ext_vector_type(8)));
typedef float f32x4 __attribute__((ext_vector_type(4)));
typedef __hip_bfloat16 bf16;

__device__ __forceinline__ void async_copy16(const void* g, void* s) {
    __builtin_amdgcn_global_load_lds(
        (const __attribute__((address_space(1))) unsigned int*)g,
        (__attribute__((address_space(3))) unsigned int*)s, 16, 0, 0);
}

// Generic NT bf16 GEMM, 128x128 tile, BK=64, 256 threads (2x2 waves), m97 structure.
// mode 0: C=bf16, (acc + bias[col]) * scale
// mode 1: C=bf16, exp(acc), block-reduced sum atomicAdd'ed to Zp[z]
// mode 2: C=bf16, acc * (1/Zp[z])
// mode 3: C=f32,  acc + bias[row]
__global__ __launch_bounds__(256)
void gemm_nt(const bf16* __restrict__ A, const bf16* __restrict__ B, void* __restrict__ Cvoid,
             int M, int N, int K, int lda, int ldb, int ldc,
             long asn, long ash, long bsn, long bsh, long csn, long csh,
             int H, int mode, const float* __restrict__ bias, float* __restrict__ Zp, float scale)
{
    __shared__ __align__(16) bf16 Alds[128 * 64];
    __shared__ __align__(16) bf16 Blds[128 * 64];

    const int tid  = threadIdx.x;
    const int wave = tid >> 6;
    const int lane = tid & 63;
    const int z  = blockIdx.z;
    const int zn = z / H, zh = z % H;

    const bf16* Ab = A + zn * asn + zh * ash;
    const bf16* Bb = B + zn * bsn + zh * bsh;

    const long tM = (long)blockIdx.y * 128;
    const long tN = (long)blockIdx.x * 128;

    const int wr   = (wave >> 1) * 64;   // M-quadrant of this wave
    const int wc   = (wave & 1) * 64;    // N-quadrant
    const int l15  = lane & 15;
    const int quad = lane >> 4;

    f32x4 acc[4][4] = {};

    const int kiters = K >> 6;
    for (int kt = 0; kt < kiters; ++kt) {
        const long kof = (long)kt * 64;
        // Stage 128 rows x 64 bf16 (128 B/row = 8 x 16B chunks): flat = row*8 + chunk.
        // Lane l of wave w at iter i has flat = i*256 + w*64 + l, and the HW writes its
        // 16 B to LDS byte (i*256+w*64)*16 + l*16 = flat*16 -> element flat*8 = row*64+kc*8,
        // which matches the compute-side read Alds[row*64 + kk*32 + quad*8]. (R1 fix: was >>2/&3.)
#pragma unroll
        for (int i = 0; i < 4; ++i) {
            const int flat = i * 256 + tid;
            const int row  = flat >> 3;
            const int kc   = flat & 7;
            const bf16* ga = Ab + (tM + row) * (long)lda + kof + kc * 8;
            const bf16* gb = Bb + (tN + row) * (long)ldb + kof + kc * 8;
            char* la = (char*)Alds + (long)(i * 256 + wave * 64) * 16;
            char* lb = (char*)Blds + (long)(i * 256 + wave * 64) * 16;
            async_copy16(ga, la);
            async_copy16(gb, lb);
        }
        __syncthreads();
#pragma unroll
        for (int kk = 0; kk < 2; ++kk) {
            bf16x8 af[4], bfv[4];
#pragma unroll
            for (int i = 0; i < 4; ++i)
                af[i] = *(const bf16x8*)(Alds + (wr + i * 16 + l15) * 64 + kk * 32 + quad * 8);
#pragma unroll
            for (int j = 0; j < 4; ++j)
                bfv[j] = *(const bf16x8*)(Blds + (wc + j * 16 + l15) * 64 + kk * 32 + quad * 8);
#pragma unroll
            for (int i = 0; i < 4; ++i)
#pragma unroll
                for (int j = 0; j < 4; ++j)
                    acc[i][j] = __builtin_amdgcn_mfma_f32_16x16x32_bf16(af[i], bfv[j], acc[i][j], 0, 0, 0);
        }
        __syncthreads();
    }

    // Epilogue. C/D layout: col = lane&15, row = quad*4 + reg (verified m89/m91).
    float zscale = 1.0f;
    if (mode == 2) zscale = 1.0f / Zp[z];
    float ssum = 0.0f;

    if (mode == 3) {
        float* C = (float*)Cvoid + zn * csn + zh * csh;
#pragma unroll
        for (int i = 0; i < 4; ++i)
#pragma unroll
            for (int j = 0; j < 4; ++j)
#pragma unroll
                for (int r = 0; r < 4; ++r) {
                    const long row = tM + wr + i * 16 + quad * 4 + r;
                    const long col = tN + wc + j * 16 + l15;
                    C[row * (long)ldc + col] = acc[i][j][r] + bias[row];
                }
    } else {
        bf16* C = (bf16*)Cvoid + zn * csn + zh * csh;
#pragma unroll
        for (int i = 0; i < 4; ++i)
#pragma unroll
            for (int j = 0; j < 4; ++j)
#pragma unroll
                for (int r = 0; r < 4; ++r) {
                    const long row = tM + wr + i * 16 + quad * 4 + r;
                    const long col = tN + wc + j * 16 + l15;
                    float v = acc[i][j][r];
                    if (mode == 0)      v = (v + bias[col]) * scale;
                    else if (mode == 1) { v = __expf(v); ssum += v; }
                    else                v *= zscale;
                    C[row * (long)ldc + col] = __float2bfloat16(v);
                }
    }
    if (mode == 1) {
        for (int o = 32; o > 0; o >>= 1) ssum += __shfl_down(ssum, o);
        if (lane == 0) atomicAdd(Zp + z, ssum);
    }
}

// Convert weights to bf16; zero the Z accumulator (ws is poisoned each call).
__global__ void prep_convert(const float* __restrict__ w_in, const float* __restrict__ w_out,
                             bf16* __restrict__ w_in_b, bf16* __restrict__ w_out_b,
                             float* __restrict__ Z)
{
    const long gid = (long)blockIdx.x * 256 + threadIdx.x;
    if (blockIdx.x == 0 && threadIdx.x < 64) Z[threadIdx.x] = 0.0f;
    const long n1 = 6144L * 256;
    const long n2 = 256L * 2048;
    const long stride = (long)gridDim.x * 256;
    for (long i = gid; i < n1; i += stride) w_in_b[i] = __float2bfloat16(w_in[i]);
    for (long i = gid; i < n2; i += stride) w_out_b[i] = __float2bfloat16(w_out[i]);
}

// x (n, 256 c, 1024 l) f32 -> x_t (n, 1024 l, 256 c) bf16, 64x64 LDS tiles.
__global__ void prep_xt(const float* __restrict__ x, bf16* __restrict__ x_t)
{
    __shared__ float tile[64][65];
    const int b = blockIdx.x;              // 4 c-tiles * 16 l-tiles
    const int n = blockIdx.y;
    const int ct = b & 3, lt = b >> 2;
    const int t = threadIdx.x;
    const float* xp = x + (long)n * 256 * 1024;
#pragma unroll
    for (int i = 0; i < 16; ++i) {
        const int flat = i * 256 + t;
        const int cl = flat >> 6, ll = flat & 63;
        tile[cl][ll] = xp[(long)(ct * 64 + cl) * 1024 + lt * 64 + ll];
    }
    __syncthreads();
    bf16* xo = x_t + (long)n * 1024 * 256;
#pragma unroll
    for (int i = 0; i < 16; ++i) {
        const int flat = i * 256 + t;
        const int lr = flat >> 6, cr = flat & 63;
        xo[(long)(lt * 64 + lr) * 256 + ct * 64 + cr] = __float2bfloat16(tile[cr][lr]);
    }
}

// v2[n,h,d,l] = scaled_t[n,l,h*768+512+d]  (bf16 -> bf16 tiled transpose)
__global__ void prep_v2(const bf16* __restrict__ scaled_t, bf16* __restrict__ v2)
{
    __shared__ bf16 tile[64][74];
    const int b  = blockIdx.x;             // 4 d-tiles * 16 l-tiles
    const int nh = blockIdx.y;
    const int dt = b & 3, lt = b >> 2;
    const int n = nh >> 3, h = nh & 7;
    const int t = threadIdx.x;
    const bf16* sp = scaled_t + (long)n * 1024 * 6144 + h * 768 + 512;
#pragma unroll
    for (int i = 0; i < 16; ++i) {
        const int flat = i * 256 + t;
        const int lr = flat >> 6, dc = flat & 63;
        tile[dc][lr] = sp[(long)(lt * 64 + lr) * 6144 + dt * 64 + dc];
    }
    __syncthreads();
    bf16* vp = v2 + ((long)nh * 256 + dt * 64) * 1024;
#pragma unroll
    for (int i = 0; i < 16; ++i) {
        const int flat = i * 256 + t;
        const int dr = flat >> 6, lc = flat & 63;
        vp[(long)dr * 1024 + lt * 64 + lc] = tile[dr][lc];
    }
}

extern "C" void kernel_launch(void* const* d_in, const int* in_sizes, int n_in,
                              void* d_out, int out_size, void* d_ws, size_t ws_size,
                              hipStream_t stream)
{
    const float* x     = (const float*)d_in[0];
    const float* w_in  = (const float*)d_in[1];
    const float* b_in  = (const float*)d_in[2];
    const float* w_out = (const float*)d_in[3];
    const float* b_out = (const float*)d_in[4];
    float* out = (float*)d_out;

    char* p = (char*)d_ws;
    bf16* scaled_t = (bf16*)p;  p += 100663296;   // (8, 1024, 6144) bf16
    bf16* v2       = (bf16*)p;  p += 33554432;    // (8, 8, 256, 1024) bf16
    bf16* out_tt   = (bf16*)p;  p += 33554432;    // (8, 1024, 2048) bf16
    bf16* Pbuf     = (bf16*)p;  p += 33554432;    // (2, 8, 1024, 1024) bf16 chunk
    bf16* x_t      = (bf16*)p;  p += 4194304;     // (8, 1024, 256) bf16
    bf16* w_in_b   = (bf16*)p;  p += 3145728;     // (6144, 256) bf16
    bf16* w_out_b  = (bf16*)p;  p += 1048576;     // (256, 2048) bf16
    float* Z       = (float*)p; p += 256;         // 64 softmax denominators

    const float SCALE = 0.10416666666666667f;     // 1/16 * sqrt(6400/2304) = 5/48

    prep_convert<<<2048, 256, 0, stream>>>(w_in, w_out, w_in_b, w_out_b, Z);
    prep_xt<<<dim3(64, 8), 256, 0, stream>>>(x, x_t);

    // g1: scaled_t[n,l,o], M=1024(l) N=6144(o) K=256(c)
    gemm_nt<<<dim3(48, 8, 8), 256, 0, stream>>>(
        x_t, w_in_b, scaled_t,
        1024, 6144, 256, 256, 256, 6144,
        1024L * 256, 0, 0, 0, 1024L * 6144, 0,
        1, 0, b_in, nullptr, SCALE);

    prep_v2<<<dim3(64, 64), 256, 0, stream>>>(scaled_t, v2);

    for (int c = 0; c < 4; ++c) {
        const long n0 = 2L * c;
        // g2: P[m,l] = exp(att), accumulate Z. batch z = (n-n0)*8 + h
        gemm_nt<<<dim3(8, 8, 16), 256, 0, stream>>>(
            scaled_t + n0 * 1024 * 6144 + 256, scaled_t + n0 * 1024 * 6144, Pbuf,
            1024, 1024, 256, 6144, 6144, 1024,
            1024L * 6144, 768, 1024L * 6144, 768, 8L * 1024 * 1024, 1024L * 1024,
            8, 1, nullptr, Z + n0 * 8, 1.0f);
        // g3: out_tt[n,m,h*256+d] = P . v2 / Z, M=1024(m) N=256(d) K=1024(l)
        gemm_nt<<<dim3(2, 8, 16), 256, 0, stream>>>(
            Pbuf, v2 + n0 * 8 * 256 * 1024, out_tt + n0 * 1024 * 2048,
            1024, 256, 1024, 1024, 1024, 2048,
            8L * 1024 * 1024, 1024L * 1024, 8L * 256 * 1024, 256L * 1024, 1024L * 2048, 256,
            8, 2, nullptr, Z + n0 * 8, 1.0f);
    }

    // g4: out[n,c,m] = w_out . out_tt + b_out, M=256(c) N=1024(m) K=2048(a)
    gemm_nt<<<dim3(8, 2, 8), 256, 0, stream>>>(
        w_out_b, out_tt, out,
        256, 1024, 2048, 2048, 2048, 1024,
        0, 0, 1024L * 2048, 0, 256L * 1024, 0,
        1, 3, b_out, nullptr, 1.0f);
}

// Round 3
// 610.194 us; speedup vs baseline: 1.0391x; 1.0391x over previous
//
#include <hip/hip_runtime.h>
#include <hip/hip_bf16.h>

// MultiHeadAttention: x(8,256,32,32) -> qkv proj -> global-softmax attention -> out proj.
// All GEMMs cast to one NT pattern: A(M,K) K-contig, B(N,K) K-contig, C(M,N) row-major.
//   g1: scaled_t[n,l,o] = (x_t[l,c] . w_in[o,c] + b_in[o]) * SCALE          (K=256)
//   g2: P[m,l] = exp(k_t[m,d] . q_t[l,d]); Z[nh] += sum                     (K=256)
//   g3: out_tt[n,m,h*256+d] = (P[m,l] . v2[d,l]) / Z[nh]                    (K=1024)
//   g4: out[n,c,m] = w_out[c,a] . out_tt[m,a] + b_out[c]                    (K=2048)
// Global softmax: att ~ N(0,0.17^2), |att|max ~ 1, so exp() without max-subtraction is safe.
// R3: XOR-swizzled LDS (kills 16-way bank conflict), un-chunked g2/g3 when ws allows.

typedef __bf16 bf16x8 __attribute__((ext_vector_type(8)));
typedef float f32x4 __attribute__((ext_vector_type(4)));
typedef __hip_bfloat16 bf16;

__device__ __forceinline__ void async_copy16(const void* g, void* s) {
    __builtin_amdgcn_global_load_lds(
        (const __attribute__((address_space(1))) unsigned int*)g,
        (__attribute__((address_space(3))) unsigned int*)s, 16, 0, 0);
}

// Generic NT bf16 GEMM, 128x128 tile, BK=64, 256 threads (2x2 waves), m97 structure.
// LDS layout: element (row, chunk_slot) at row*64 + chunk_slot*8, where the data held in
// chunk_slot is global chunk (chunk_slot ^ (row&7)).  global_load_lds forces linear
// lane->LDS placement, so the swizzle is applied on the global SOURCE address at staging
// and undone at the fragment read: 16 lanes of a quad (rows l15=0..15, fixed logical
// chunk) then hit 8 distinct chunk slots -> all 32 banks 2-way = conflict-free (m136).
// mode 0: C=bf16, (acc + bias[col]) * scale
// mode 1: C=bf16, exp(acc), per-wave sum atomicAdd'ed to Zp[z]
// mode 2: C=bf16, acc * (1/Zp[z])
// mode 3: C=f32,  acc + bias[row]
__global__ __launch_bounds__(256)
void gemm_nt(const bf16* __restrict__ A, const bf16* __restrict__ B, void* __restrict__ Cvoid,
             int M, int N, int K, int lda, int ldb, int ldc,
             long asn, long ash, long bsn, long bsh, long csn, long csh,
             int H, int mode, const float* __restrict__ bias, float* __restrict__ Zp, float scale)
{
    __shared__ __align__(16) bf16 Alds[128 * 64];
    __shared__ __align__(16) bf16 Blds[128 * 64];

    const int tid  = threadIdx.x;
    const int wave = tid >> 6;
    const int lane = tid & 63;
    const int z  = blockIdx.z;
    const int zn = z / H, zh = z % H;

    const bf16* Ab = A + zn * asn + zh * ash;
    const bf16* Bb = B + zn * bsn + zh * bsh;

    const long tM = (long)blockIdx.y * 128;
    const long tN = (long)blockIdx.x * 128;

    const int wr   = (wave >> 1) * 64;   // M-quadrant of this wave
    const int wc   = (wave & 1) * 64;    // N-quadrant
    const int l15  = lane & 15;
    const int quad = lane >> 4;

    f32x4 acc[4][4] = {};

    const int kiters = K >> 6;
    for (int kt = 0; kt < kiters; ++kt) {
        const long kof = (long)kt * 64;
        // Stage 128 rows x 64 bf16: flat = row*8 + chunk_slot; HW writes lane's 16B at
        // LDS byte flat*16. Source chunk is XOR-swizzled (see header comment).
#pragma unroll
        for (int i = 0; i < 4; ++i) {
            const int flat = i * 256 + tid;
            const int row  = flat >> 3;
            const int kcs  = (flat & 7) ^ (row & 7);   // swizzled source chunk
            const bf16* ga = Ab + (tM + row) * (long)lda + kof + kcs * 8;
            const bf16* gb = Bb + (tN + row) * (long)ldb + kof + kcs * 8;
            char* la = (char*)Alds + (long)(i * 256 + wave * 64) * 16;
            char* lb = (char*)Blds + (long)(i * 256 + wave * 64) * 16;
            async_copy16(ga, la);
            async_copy16(gb, lb);
        }
        __syncthreads();
#pragma unroll
        for (int kk = 0; kk < 2; ++kk) {
            bf16x8 af[4], bfv[4];
#pragma unroll
            for (int i = 0; i < 4; ++i) {
                const int r = wr + i * 16 + l15;
                af[i] = *(const bf16x8*)(Alds + r * 64 + ((kk * 4 + quad) ^ (r & 7)) * 8);
            }
#pragma unroll
            for (int j = 0; j < 4; ++j) {
                const int r = wc + j * 16 + l15;
                bfv[j] = *(const bf16x8*)(Blds + r * 64 + ((kk * 4 + quad) ^ (r & 7)) * 8);
            }
#pragma unroll
            for (int i = 0; i < 4; ++i)
#pragma unroll
                for (int j = 0; j < 4; ++j)
                    acc[i][j] = __builtin_amdgcn_mfma_f32_16x16x32_bf16(af[i], bfv[j], acc[i][j], 0, 0, 0);
        }
        __syncthreads();
    }

    // Epilogue. C/D layout: col = lane&15, row = quad*4 + reg (verified m89/m91).
    float zscale = 1.0f;
    if (mode == 2) zscale = 1.0f / Zp[z];
    float ssum = 0.0f;

    if (mode == 3) {
        float* C = (float*)Cvoid + zn * csn + zh * csh;
#pragma unroll
        for (int i = 0; i < 4; ++i)
#pragma unroll
            for (int j = 0; j < 4; ++j)
#pragma unroll
                for (int r = 0; r < 4; ++r) {
                    const long row = tM + wr + i * 16 + quad * 4 + r;
                    const long col = tN + wc + j * 16 + l15;
                    C[row * (long)ldc + col] = acc[i][j][r] + bias[row];
                }
    } else {
        bf16* C = (bf16*)Cvoid + zn * csn + zh * csh;
#pragma unroll
        for (int i = 0; i < 4; ++i)
#pragma unroll
            for (int j = 0; j < 4; ++j)
#pragma unroll
                for (int r = 0; r < 4; ++r) {
                    const long row = tM + wr + i * 16 + quad * 4 + r;
                    const long col = tN + wc + j * 16 + l15;
                    float v = acc[i][j][r];
                    if (mode == 0)      v = (v + bias[col]) * scale;
                    else if (mode == 1) { v = __expf(v); ssum += v; }
                    else                v *= zscale;
                    C[row * (long)ldc + col] = __float2bfloat16(v);
                }
    }
    if (mode == 1) {
        for (int o = 32; o > 0; o >>= 1) ssum += __shfl_down(ssum, o);
        if (lane == 0) atomicAdd(Zp + z, ssum);
    }
}

// Convert weights to bf16; zero the Z accumulator (ws is poisoned each call).
__global__ void prep_convert(const float* __restrict__ w_in, const float* __restrict__ w_out,
                             bf16* __restrict__ w_in_b, bf16* __restrict__ w_out_b,
                             float* __restrict__ Z)
{
    const long gid = (long)blockIdx.x * 256 + threadIdx.x;
    if (blockIdx.x == 0 && threadIdx.x < 64) Z[threadIdx.x] = 0.0f;
    const long n1 = 6144L * 256;
    const long n2 = 256L * 2048;
    const long stride = (long)gridDim.x * 256;
    for (long i = gid; i < n1; i += stride) w_in_b[i] = __float2bfloat16(w_in[i]);
    for (long i = gid; i < n2; i += stride) w_out_b[i] = __float2bfloat16(w_out[i]);
}

// x (n, 256 c, 1024 l) f32 -> x_t (n, 1024 l, 256 c) bf16, 64x64 LDS tiles.
__global__ void prep_xt(const float* __restrict__ x, bf16* __restrict__ x_t)
{
    __shared__ float tile[64][65];
    const int b = blockIdx.x;              // 4 c-tiles * 16 l-tiles
    const int n = blockIdx.y;
    const int ct = b & 3, lt = b >> 2;
    const int t = threadIdx.x;
    const float* xp = x + (long)n * 256 * 1024;
#pragma unroll
    for (int i = 0; i < 16; ++i) {
        const int flat = i * 256 + t;
        const int cl = flat >> 6, ll = flat & 63;
        tile[cl][ll] = xp[(long)(ct * 64 + cl) * 1024 + lt * 64 + ll];
    }
    __syncthreads();
    bf16* xo = x_t + (long)n * 1024 * 256;
#pragma unroll
    for (int i = 0; i < 16; ++i) {
        const int flat = i * 256 + t;
        const int lr = flat >> 6, cr = flat & 63;
        xo[(long)(lt * 64 + lr) * 256 + ct * 64 + cr] = __float2bfloat16(tile[cr][lr]);
    }
}

// v2[n,h,d,l] = scaled_t[n,l,h*768+512+d]  (bf16 -> bf16 tiled transpose)
__global__ void prep_v2(const bf16* __restrict__ scaled_t, bf16* __restrict__ v2)
{
    __shared__ bf16 tile[64][74];
    const int b  = blockIdx.x;             // 4 d-tiles * 16 l-tiles
    const int nh = blockIdx.y;
    const int dt = b & 3, lt = b >> 2;
    const int n = nh >> 3, h = nh & 7;
    const int t = threadIdx.x;
    const bf16* sp = scaled_t + (long)n * 1024 * 6144 + h * 768 + 512;
#pragma unroll
    for (int i = 0; i < 16; ++i) {
        const int flat = i * 256 + t;
        const int lr = flat >> 6, dc = flat & 63;
        tile[dc][lr] = sp[(long)(lt * 64 + lr) * 6144 + dt * 64 + dc];
    }
    __syncthreads();
    bf16* vp = v2 + ((long)nh * 256 + dt * 64) * 1024;
#pragma unroll
    for (int i = 0; i < 16; ++i) {
        const int flat = i * 256 + t;
        const int dr = flat >> 6, lc = flat & 63;
        vp[(long)dr * 1024 + lt * 64 + lc] = tile[dr][lc];
    }
}

extern "C" void kernel_launch(void* const* d_in, const int* in_sizes, int n_in,
                              void* d_out, int out_size, void* d_ws, size_t ws_size,
                              hipStream_t stream)
{
    const float* x     = (const float*)d_in[0];
    const float* w_in  = (const float*)d_in[1];
    const float* b_in  = (const float*)d_in[2];
    const float* w_out = (const float*)d_in[3];
    const float* b_out = (const float*)d_in[4];
    float* out = (float*)d_out;

    const float SCALE = 0.10416666666666667f;     // 1/16 * sqrt(6400/2304) = 5/48

    // Full (un-chunked) layout needs ~303 MB; chunked fallback needs ~210 MB (known OK).
    const size_t FULL_NEED = 134217728UL + 100663296UL + 33554432UL + 33554432UL + 1048576UL + 256UL;
    const bool full = (ws_size >= FULL_NEED);

    char* p = (char*)d_ws;
    bf16 *scaled_t, *v2, *out_tt, *Pbuf, *x_t, *w_in_b, *w_out_b;
    float* Z;
    if (full) {
        Pbuf     = (bf16*)p;  p += 134217728;     // (8, 8, 1024, 1024) bf16 full P
        scaled_t = (bf16*)p;  p += 100663296;     // (8, 1024, 6144) bf16
        v2       = (bf16*)p;  p += 33554432;      // (8, 8, 256, 1024) bf16
        out_tt   = (bf16*)p;  p += 33554432;      // (8, 1024, 2048) bf16
        w_out_b  = (bf16*)p;  p += 1048576;       // (256, 2048) bf16
        Z        = (float*)p; p += 256;           // 64 softmax denominators
        // x_t / w_in_b are dead before Pbuf is written -> overlay into Pbuf space
        x_t      = (bf16*)Pbuf;                   // (8, 1024, 256) bf16, 4.2 MB
        w_in_b   = (bf16*)((char*)Pbuf + 4194304);// (6144, 256) bf16, 3.1 MB
    } else {
        scaled_t = (bf16*)p;  p += 100663296;
        v2       = (bf16*)p;  p += 33554432;
        out_tt   = (bf16*)p;  p += 33554432;
        Pbuf     = (bf16*)p;  p += 33554432;      // (2, 8, 1024, 1024) chunk
        x_t      = (bf16*)p;  p += 4194304;
        w_in_b   = (bf16*)p;  p += 3145728;
        w_out_b  = (bf16*)p;  p += 1048576;
        Z        = (float*)p; p += 256;
    }

    prep_convert<<<2048, 256, 0, stream>>>(w_in, w_out, w_in_b, w_out_b, Z);
    prep_xt<<<dim3(64, 8), 256, 0, stream>>>(x, x_t);

    // g1: scaled_t[n,l,o], M=1024(l) N=6144(o) K=256(c)
    gemm_nt<<<dim3(48, 8, 8), 256, 0, stream>>>(
        x_t, w_in_b, scaled_t,
        1024, 6144, 256, 256, 256, 6144,
        1024L * 256, 0, 0, 0, 1024L * 6144, 0,
        1, 0, b_in, nullptr, SCALE);

    prep_v2<<<dim3(64, 64), 256, 0, stream>>>(scaled_t, v2);

    if (full) {
        // g2: P[m,l] = exp(k.q), accumulate Z; z = n*8+h over all 64 heads
        gemm_nt<<<dim3(8, 8, 64), 256, 0, stream>>>(
            scaled_t + 256, scaled_t, Pbuf,
            1024, 1024, 256, 6144, 6144, 1024,
            1024L * 6144, 768, 1024L * 6144, 768, 8L * 1024 * 1024, 1024L * 1024,
            8, 1, nullptr, Z, 1.0f);
        // g3: out_tt[n,m,h*256+d] = P . v2 / Z, M=1024(m) N=256(d) K=1024(l)
        gemm_nt<<<dim3(2, 8, 64), 256, 0, stream>>>(
            Pbuf, v2, out_tt,
            1024, 256, 1024, 1024, 1024, 2048,
            8L * 1024 * 1024, 1024L * 1024, 8L * 256 * 1024, 256L * 1024, 1024L * 2048, 256,
            8, 2, nullptr, Z, 1.0f);
    } else {
        for (int c = 0; c < 4; ++c) {
            const long n0 = 2L * c;
            gemm_nt<<<dim3(8, 8, 16), 256, 0, stream>>>(
                scaled_t + n0 * 1024 * 6144 + 256, scaled_t + n0 * 1024 * 6144, Pbuf,
                1024, 1024, 256, 6144, 6144, 1024,
                1024L * 6144, 768, 1024L * 6144, 768, 8L * 1024 * 1024, 1024L * 1024,
                8, 1, nullptr, Z + n0 * 8, 1.0f);
            gemm_nt<<<dim3(2, 8, 16), 256, 0, stream>>>(
                Pbuf, v2 + n0 * 8 * 256 * 1024, out_tt + n0 * 1024 * 2048,
                1024, 256, 1024, 1024, 1024, 2048,
                8L * 1024 * 1024, 1024L * 1024, 8L * 256 * 1024, 256L * 1024, 1024L * 2048, 256,
                8, 2, nullptr, Z + n0 * 8, 1.0f);
        }
    }

    // g4: out[n,c,m] = w_out . out_tt + b_out, M=256(c) N=1024(m) K=2048(a)
    gemm_nt<<<dim3(8, 2, 8), 256, 0, stream>>>(
        w_out_b, out_tt, out,
        256, 1024, 2048, 2048, 2048, 1024,
        0, 0, 1024L * 2048, 0, 256L * 1024, 0,
        1, 3, b_out, nullptr, 1.0f);
}

// Round 4
// 554.509 us; speedup vs baseline: 1.1434x; 1.1004x over previous
//
#include <hip/hip_runtime.h>
#include <hip/hip_bf16.h>

// MultiHeadAttention: x(8,256,32,32) -> qkv proj -> global-softmax attention -> out proj.
// All GEMMs cast to one NT pattern: A(M,K) K-contig, B(N,K) K-contig, C(M,N) row-major.
//   g1: scaled_t[n,l,o] = (x_t[l,c] . w_in[o,c] + b_in[o]) * SCALE          (K=256)
//   g2: P[m,l] = exp(k_t[m,d] . q_t[l,d]); Z[nh] += sum                     (K=256)
//   g3: out_tt[n,m,h*256+d] = (P[m,l] . v2[d,l]) / Z[nh]                    (K=1024)
//   g4: out[n,c,m] = w_out[c,a] . out_tt[m,a] + b_out[c]                    (K=2048)
// Global softmax: att ~ N(0,0.17^2), |att|max ~ 1, so exp() without max-subtraction is safe.
// R4: register-prefetch pipelined K-loop (raw s_barrier, no vmcnt drain on the WAR barrier)
//     + LDS-staged vectorized epilogue. R3's XOR bank-conflict swizzle retained.

typedef __bf16 bf16x8 __attribute__((ext_vector_type(8)));
typedef float f32x4 __attribute__((ext_vector_type(4)));
typedef __hip_bfloat16 bf16;

__device__ __forceinline__ void async_copy16(const void* g, void* s) {
    __builtin_amdgcn_global_load_lds(
        (const __attribute__((address_space(1))) unsigned int*)g,
        (__attribute__((address_space(3))) unsigned int*)s, 16, 0, 0);
}

// Generic NT bf16 GEMM, 128x128 tile, BK=64, 256 threads (2x2 waves).
// K-loop pipeline: glds stages step 0; each iter prefetches step k+1 into VGPRs
// (overlapping step k's MFMA), then crosses a RAW s_barrier (reads already consumed,
// so no vmcnt drain needed for the write-after-read hazard) and ds_writes the regs.
// LDS layout (both A and B): element (row, slot) at row*64 + slot*8; slot holds global
// chunk slot^(row&7) (XOR swizzle -> conflict-free quad reads, verified R3: conflicts=0).
// mode 0: C=bf16, (acc + bias[col]) * scale
// mode 1: C=bf16, exp(acc), per-wave sum atomicAdd'ed to Zp[z]
// mode 2: C=bf16, acc * (1/Zp[z])
// mode 3: C=f32,  acc + bias[row]  (scalar-store path; only used by small g4)
__global__ __launch_bounds__(256)
void gemm_nt(const bf16* __restrict__ A, const bf16* __restrict__ B, void* __restrict__ Cvoid,
             int M, int N, int K, int lda, int ldb, int ldc,
             long asn, long ash, long bsn, long bsh, long csn, long csh,
             int H, int mode, const float* __restrict__ bias, float* __restrict__ Zp, float scale)
{
    // [0,8192) A-tile, [8192,16384) B-tile; epilogue reuses all 17408 as 128x136 C-stage.
    __shared__ __align__(16) bf16 smem[17408];
    bf16* Alds = smem;
    bf16* Blds = smem + 8192;

    const int tid  = threadIdx.x;
    const int wave = tid >> 6;
    const int lane = tid & 63;
    const int z  = blockIdx.z;
    const int zn = z / H, zh = z % H;

    const bf16* Ab = A + zn * asn + zh * ash;
    const bf16* Bb = B + zn * bsn + zh * bsh;

    const long tM = (long)blockIdx.y * 128;
    const long tN = (long)blockIdx.x * 128;

    const int wr   = (wave >> 1) * 64;   // M-quadrant of this wave
    const int wc   = (wave & 1) * 64;    // N-quadrant
    const int l15  = lane & 15;
    const int quad = lane >> 4;

    f32x4 acc[4][4] = {};

    const int kiters = K >> 6;

    // Prologue: async-stage step 0 via global_load_lds (wave-uniform LDS base + lane*16).
#pragma unroll
    for (int i = 0; i < 4; ++i) {
        const int flat = i * 256 + tid;
        const int row  = flat >> 3;
        const int kcs  = (flat & 7) ^ (row & 7);
        async_copy16(Ab + (tM + row) * (long)lda + kcs * 8,
                     (char*)Alds + (long)(i * 256 + wave * 64) * 16);
        async_copy16(Bb + (tN + row) * (long)ldb + kcs * 8,
                     (char*)Blds + (long)(i * 256 + wave * 64) * 16);
    }

    bf16x8 pfA[4], pfB[4];
    for (int kt = 0; kt < kiters; ++kt) {
        __syncthreads();   // drains glds (kt=0) / own ds_writes (kt>0); vmem queue empty otherwise
        const bool has_next = (kt + 1 < kiters);
        if (has_next) {
            const long kof = (long)(kt + 1) * 64;
#pragma unroll
            for (int i = 0; i < 4; ++i) {
                const int flat = i * 256 + tid;
                const int row  = flat >> 3;
                const int kcs  = (flat & 7) ^ (row & 7);
                pfA[i] = *(const bf16x8*)(Ab + (tM + row) * (long)lda + kof + kcs * 8);
                pfB[i] = *(const bf16x8*)(Bb + (tN + row) * (long)ldb + kof + kcs * 8);
            }
        }
#pragma unroll
        for (int kk = 0; kk < 2; ++kk) {
            bf16x8 af[4], bfv[4];
#pragma unroll
            for (int i = 0; i < 4; ++i) {
                const int r = wr + i * 16 + l15;
                af[i] = *(const bf16x8*)(Alds + r * 64 + ((kk * 4 + quad) ^ (r & 7)) * 8);
            }
#pragma unroll
            for (int j = 0; j < 4; ++j) {
                const int r = wc + j * 16 + l15;
                bfv[j] = *(const bf16x8*)(Blds + r * 64 + ((kk * 4 + quad) ^ (r & 7)) * 8);
            }
#pragma unroll
            for (int i = 0; i < 4; ++i)
#pragma unroll
                for (int j = 0; j < 4; ++j)
                    acc[i][j] = __builtin_amdgcn_mfma_f32_16x16x32_bf16(af[i], bfv[j], acc[i][j], 0, 0, 0);
        }
        if (has_next) {
            // Raw barrier: every wave's ds_reads are consumed (lgkm-waited before MFMA use),
            // so WAR across waves is safe WITHOUT draining the in-flight prefetch loads.
            __builtin_amdgcn_sched_barrier(0);
            __builtin_amdgcn_s_barrier();
            __builtin_amdgcn_sched_barrier(0);
            // Compiler inserts vmcnt wait for pfA/pfB here -> loads overlapped all of compute.
#pragma unroll
            for (int i = 0; i < 4; ++i) {
                const int flat = i * 256 + tid;
                *(bf16x8*)((char*)Alds + (long)flat * 16) = pfA[i];
                *(bf16x8*)((char*)Blds + (long)flat * 16) = pfB[i];
            }
        }
    }

    // Epilogue. C/D layout: col = lane&15, row = quad*4 + reg (verified m89/m91).
    if (mode == 3) {
        float* C = (float*)Cvoid + zn * csn + zh * csh;
#pragma unroll
        for (int i = 0; i < 4; ++i)
#pragma unroll
            for (int j = 0; j < 4; ++j)
#pragma unroll
                for (int r = 0; r < 4; ++r) {
                    const long row = tM + wr + i * 16 + quad * 4 + r;
                    const long col = tN + wc + j * 16 + l15;
                    C[row * (long)ldc + col] = acc[i][j][r] + bias[row];
                }
    } else {
        float zscale = 1.0f;
        if (mode == 2) zscale = 1.0f / Zp[z];
        float ssum = 0.0f;
        bf16* Cb = (bf16*)Cvoid + zn * csn + zh * csh + tM * (long)ldc + tN;
        __syncthreads();   // everyone done with A/B tiles; reuse smem as 128x136 C-stage
#pragma unroll
        for (int i = 0; i < 4; ++i)
#pragma unroll
            for (int j = 0; j < 4; ++j)
#pragma unroll
                for (int r = 0; r < 4; ++r) {
                    const int row = wr + i * 16 + quad * 4 + r;
                    const int col = wc + j * 16 + l15;
                    float v = acc[i][j][r];
                    if (mode == 0)      v = (v + bias[col]) * scale;
                    else if (mode == 1) { v = __expf(v); ssum += v; }
                    else                v *= zscale;
                    smem[row * 136 + col] = __float2bfloat16(v);
                }
        if (mode == 1) {
            for (int o = 32; o > 0; o >>= 1) ssum += __shfl_down(ssum, o);
            if (lane == 0) atomicAdd(Zp + z, ssum);
        }
        __syncthreads();
        // 2048 16B-chunks (128 rows x 16); lanes 0..15 cover one row's 256 B contiguously.
        // LDS stride 272 B = 17 quad-banks -> conflict-free phases.
#pragma unroll
        for (int k = 0; k < 8; ++k) {
            const int fc  = k * 256 + tid;
            const int row = fc >> 4, cc = fc & 15;
            const f32x4 val = *(const f32x4*)((const char*)smem + row * 272 + cc * 16);
            *(f32x4*)((char*)(Cb + (long)row * ldc) + cc * 16) = val;
        }
    }
}

// Convert weights to bf16; zero the Z accumulator (ws is poisoned each call).
__global__ void prep_convert(const float* __restrict__ w_in, const float* __restrict__ w_out,
                             bf16* __restrict__ w_in_b, bf16* __restrict__ w_out_b,
                             float* __restrict__ Z)
{
    const long gid = (long)blockIdx.x * 256 + threadIdx.x;
    if (blockIdx.x == 0 && threadIdx.x < 64) Z[threadIdx.x] = 0.0f;
    const long n1 = 6144L * 256;
    const long n2 = 256L * 2048;
    const long stride = (long)gridDim.x * 256;
    for (long i = gid; i < n1; i += stride) w_in_b[i] = __float2bfloat16(w_in[i]);
    for (long i = gid; i < n2; i += stride) w_out_b[i] = __float2bfloat16(w_out[i]);
}

// x (n, 256 c, 1024 l) f32 -> x_t (n, 1024 l, 256 c) bf16, 64x64 LDS tiles.
__global__ void prep_xt(const float* __restrict__ x, bf16* __restrict__ x_t)
{
    __shared__ float tile[64][65];
    const int b = blockIdx.x;              // 4 c-tiles * 16 l-tiles
    const int n = blockIdx.y;
    const int ct = b & 3, lt = b >> 2;
    const int t = threadIdx.x;
    const float* xp = x + (long)n * 256 * 1024;
#pragma unroll
    for (int i = 0; i < 16; ++i) {
        const int flat = i * 256 + t;
        const int cl = flat >> 6, ll = flat & 63;
        tile[cl][ll] = xp[(long)(ct * 64 + cl) * 1024 + lt * 64 + ll];
    }
    __syncthreads();
    bf16* xo = x_t + (long)n * 1024 * 256;
#pragma unroll
    for (int i = 0; i < 16; ++i) {
        const int flat = i * 256 + t;
        const int lr = flat >> 6, cr = flat & 63;
        xo[(long)(lt * 64 + lr) * 256 + ct * 64 + cr] = __float2bfloat16(tile[cr][lr]);
    }
}

// v2[n,h,d,l] = scaled_t[n,l,h*768+512+d]  (bf16 -> bf16 tiled transpose)
__global__ void prep_v2(const bf16* __restrict__ scaled_t, bf16* __restrict__ v2)
{
    __shared__ bf16 tile[64][74];
    const int b  = blockIdx.x;             // 4 d-tiles * 16 l-tiles
    const int nh = blockIdx.y;
    const int dt = b & 3, lt = b >> 2;
    const int n = nh >> 3, h = nh & 7;
    const int t = threadIdx.x;
    const bf16* sp = scaled_t + (long)n * 1024 * 6144 + h * 768 + 512;
#pragma unroll
    for (int i = 0; i < 16; ++i) {
        const int flat = i * 256 + t;
        const int lr = flat >> 6, dc = flat & 63;
        tile[dc][lr] = sp[(long)(lt * 64 + lr) * 6144 + dt * 64 + dc];
    }
    __syncthreads();
    bf16* vp = v2 + ((long)nh * 256 + dt * 64) * 1024;
#pragma unroll
    for (int i = 0; i < 16; ++i) {
        const int flat = i * 256 + t;
        const int dr = flat >> 6, lc = flat & 63;
        vp[(long)dr * 1024 + lt * 64 + lc] = tile[dr][lc];
    }
}

extern "C" void kernel_launch(void* const* d_in, const int* in_sizes, int n_in,
                              void* d_out, int out_size, void* d_ws, size_t ws_size,
                              hipStream_t stream)
{
    const float* x     = (const float*)d_in[0];
    const float* w_in  = (const float*)d_in[1];
    const float* b_in  = (const float*)d_in[2];
    const float* w_out = (const float*)d_in[3];
    const float* b_out = (const float*)d_in[4];
    float* out = (float*)d_out;

    const float SCALE = 0.10416666666666667f;     // 1/16 * sqrt(6400/2304) = 5/48

    // Full (un-chunked) layout needs ~303 MB; chunked fallback needs ~210 MB (known OK).
    const size_t FULL_NEED = 134217728UL + 100663296UL + 33554432UL + 33554432UL + 1048576UL + 256UL;
    const bool full = (ws_size >= FULL_NEED);

    char* p = (char*)d_ws;
    bf16 *scaled_t, *v2, *out_tt, *Pbuf, *x_t, *w_in_b, *w_out_b;
    float* Z;
    if (full) {
        Pbuf     = (bf16*)p;  p += 134217728;     // (8, 8, 1024, 1024) bf16 full P
        scaled_t = (bf16*)p;  p += 100663296;     // (8, 1024, 6144) bf16
        v2       = (bf16*)p;  p += 33554432;      // (8, 8, 256, 1024) bf16
        out_tt   = (bf16*)p;  p += 33554432;      // (8, 1024, 2048) bf16
        w_out_b  = (bf16*)p;  p += 1048576;       // (256, 2048) bf16
        Z        = (float*)p; p += 256;           // 64 softmax denominators
        // x_t / w_in_b are dead before Pbuf is written -> overlay into Pbuf space
        x_t      = (bf16*)Pbuf;                   // (8, 1024, 256) bf16, 4.2 MB
        w_in_b   = (bf16*)((char*)Pbuf + 4194304);// (6144, 256) bf16, 3.1 MB
    } else {
        scaled_t = (bf16*)p;  p += 100663296;
        v2       = (bf16*)p;  p += 33554432;
        out_tt   = (bf16*)p;  p += 33554432;
        Pbuf     = (bf16*)p;  p += 33554432;      // (2, 8, 1024, 1024) chunk
        x_t      = (bf16*)p;  p += 4194304;
        w_in_b   = (bf16*)p;  p += 3145728;
        w_out_b  = (bf16*)p;  p += 1048576;
        Z        = (float*)p; p += 256;
    }

    prep_convert<<<2048, 256, 0, stream>>>(w_in, w_out, w_in_b, w_out_b, Z);
    prep_xt<<<dim3(64, 8), 256, 0, stream>>>(x, x_t);

    // g1: scaled_t[n,l,o], M=1024(l) N=6144(o) K=256(c)
    gemm_nt<<<dim3(48, 8, 8), 256, 0, stream>>>(
        x_t, w_in_b, scaled_t,
        1024, 6144, 256, 256, 256, 6144,
        1024L * 256, 0, 0, 0, 1024L * 6144, 0,
        1, 0, b_in, nullptr, SCALE);

    prep_v2<<<dim3(64, 64), 256, 0, stream>>>(scaled_t, v2);

    if (full) {
        // g2: P[m,l] = exp(k.q), accumulate Z; z = n*8+h over all 64 heads
        gemm_nt<<<dim3(8, 8, 64), 256, 0, stream>>>(
            scaled_t + 256, scaled_t, Pbuf,
            1024, 1024, 256, 6144, 6144, 1024,
            1024L * 6144, 768, 1024L * 6144, 768, 8L * 1024 * 1024, 1024L * 1024,
            8, 1, nullptr, Z, 1.0f);
        // g3: out_tt[n,m,h*256+d] = P . v2 / Z, M=1024(m) N=256(d) K=1024(l)
        gemm_nt<<<dim3(2, 8, 64), 256, 0, stream>>>(
            Pbuf, v2, out_tt,
            1024, 256, 1024, 1024, 1024, 2048,
            8L * 1024 * 1024, 1024L * 1024, 8L * 256 * 1024, 256L * 1024, 1024L * 2048, 256,
            8, 2, nullptr, Z, 1.0f);
    } else {
        for (int c = 0; c < 4; ++c) {
            const long n0 = 2L * c;
            gemm_nt<<<dim3(8, 8, 16), 256, 0, stream>>>(
                scaled_t + n0 * 1024 * 6144 + 256, scaled_t + n0 * 1024 * 6144, Pbuf,
                1024, 1024, 256, 6144, 6144, 1024,
                1024L * 6144, 768, 1024L * 6144, 768, 8L * 1024 * 1024, 1024L * 1024,
                8, 1, nullptr, Z + n0 * 8, 1.0f);
            gemm_nt<<<dim3(2, 8, 16), 256, 0, stream>>>(
                Pbuf, v2 + n0 * 8 * 256 * 1024, out_tt + n0 * 1024 * 2048,
                1024, 256, 1024, 1024, 1024, 2048,
                8L * 1024 * 1024, 1024L * 1024, 8L * 256 * 1024, 256L * 1024, 1024L * 2048, 256,
                8, 2, nullptr, Z + n0 * 8, 1.0f);
        }
    }

    // g4: out[n,c,m] = w_out . out_tt + b_out, M=256(c) N=1024(m) K=2048(a)
    gemm_nt<<<dim3(8, 2, 8), 256, 0, stream>>>(
        w_out_b, out_tt, out,
        256, 1024, 2048, 2048, 2048, 1024,
        0, 0, 1024L * 2048, 0, 256L * 1024, 0,
        1, 3, b_out, nullptr, 1.0f);
}

// Round 5
// 326.819 us; speedup vs baseline: 1.9400x; 1.6967x over previous
//
#include <hip/hip_runtime.h>
#include <hip/hip_bf16.h>

// MultiHeadAttention: x(8,256,32,32) -> qkv proj -> global-softmax attention -> out proj.
//   g1 (gemm_nt mode 0): scaled_t[n,l,o] = (x_t . w_in + b_in) * SCALE       (K=256)
//   attn_fused:          out_tt[n,m,h*256+d] = Sum_l exp(q_l.k_m) v[d,l]  (UNNORMALIZED)
//                        Z[nh] = Sum exp(q.k)  (global softmax denominator)
//   g4 (gemm_nt mode 4): out[n,c,m] = w_out . (out_tt/Z) + b_out  (1/Z applied at B-staging)
// Global softmax: att ~ N(0,0.17^2), so exp() without max-subtraction is safe; softmax is
// over the whole L*L matrix per (n,h), so Z is a scalar per head (not per row).
// R5: fused g2+g3 (kills 268 MB Pbuf HBM round-trip), Z-normalization folded into g4.

typedef __bf16 bf16x8 __attribute__((ext_vector_type(8)));
typedef __bf16 bf16x4 __attribute__((ext_vector_type(4)));
typedef float f32x4 __attribute__((ext_vector_type(4)));
typedef __hip_bfloat16 bf16;

__device__ __forceinline__ void async_copy16(const void* g, void* s) {
    __builtin_amdgcn_global_load_lds(
        (const __attribute__((address_space(1))) unsigned int*)g,
        (__attribute__((address_space(3))) unsigned int*)s, 16, 0, 0);
}

__device__ __forceinline__ bf16x8 scale8(bf16x8 v, float s) {
    bf16x8 r;
#pragma unroll
    for (int e = 0; e < 8; ++e) r[e] = (__bf16)((float)v[e] * s);
    return r;
}

// ---------------------------------------------------------------------------
// Generic NT bf16 GEMM, 128x128 tile, BK=64, 256 threads (2x2 waves).
// Register-prefetch pipelined K-loop (R4), XOR-swizzled LDS (R3, 0 conflicts).
// mode 0: C=bf16, (acc + bias[col]) * scale
// mode 3: C=f32,  acc + bias[row]
// mode 4: C=f32,  acc + bias[row]; B scaled by 1/Zp[zn*8 + k/256] during staging
__global__ __launch_bounds__(256)
void gemm_nt(const bf16* __restrict__ A, const bf16* __restrict__ B, void* __restrict__ Cvoid,
             int M, int N, int K, int lda, int ldb, int ldc,
             long asn, long ash, long bsn, long bsh, long csn, long csh,
             int H, int mode, const float* __restrict__ bias, const float* __restrict__ Zp,
             float scale)
{
    __shared__ __align__(16) bf16 smem[17408];
    bf16* Alds = smem;
    bf16* Blds = smem + 8192;

    const int tid  = threadIdx.x;
    const int wave = tid >> 6;
    const int lane = tid & 63;
    const int z  = blockIdx.z;
    const int zn = z / H, zh = z % H;

    const bf16* Ab = A + zn * asn + zh * ash;
    const bf16* Bb = B + zn * bsn + zh * bsh;

    const long tM = (long)blockIdx.y * 128;
    const long tN = (long)blockIdx.x * 128;

    const int wr   = (wave >> 1) * 64;
    const int wc   = (wave & 1) * 64;
    const int l15  = lane & 15;
    const int quad = lane >> 4;

    f32x4 acc[4][4] = {};

    const int kiters = K >> 6;
    const bool regB = (mode == 4);

    // Prologue: stage step 0. A via global_load_lds; B via registers when mode 4
    // (so the 1/Z scale can be applied before the LDS write).
#pragma unroll
    for (int i = 0; i < 4; ++i) {
        const int flat = i * 256 + tid;
        const int row  = flat >> 3;
        const int kcs  = (flat & 7) ^ (row & 7);
        async_copy16(Ab + (tM + row) * (long)lda + kcs * 8,
                     (char*)Alds + (long)(i * 256 + wave * 64) * 16);
        if (!regB) {
            async_copy16(Bb + (tN + row) * (long)ldb + kcs * 8,
                         (char*)Blds + (long)(i * 256 + wave * 64) * 16);
        }
    }
    if (regB) {
        const float zi0 = 1.0f / Zp[zn * 8];
#pragma unroll
        for (int i = 0; i < 4; ++i) {
            const int flat = i * 256 + tid;
            const int row  = flat >> 3;
            const int kcs  = (flat & 7) ^ (row & 7);
            bf16x8 b = *(const bf16x8*)(Bb + (tN + row) * (long)ldb + kcs * 8);
            *(bf16x8*)((char*)Blds + (long)flat * 16) = scale8(b, zi0);
        }
    }

    bf16x8 pfA[4], pfB[4];
    for (int kt = 0; kt < kiters; ++kt) {
        __syncthreads();
        const bool has_next = (kt + 1 < kiters);
        float zin = 1.0f;
        if (has_next) {
            const long kof = (long)(kt + 1) * 64;
            if (regB) zin = 1.0f / Zp[zn * 8 + ((kt + 1) >> 2)];
#pragma unroll
            for (int i = 0; i < 4; ++i) {
                const int flat = i * 256 + tid;
                const int row  = flat >> 3;
                const int kcs  = (flat & 7) ^ (row & 7);
                pfA[i] = *(const bf16x8*)(Ab + (tM + row) * (long)lda + kof + kcs * 8);
                pfB[i] = *(const bf16x8*)(Bb + (tN + row) * (long)ldb + kof + kcs * 8);
            }
        }
#pragma unroll
        for (int kk = 0; kk < 2; ++kk) {
            bf16x8 af[4], bfv[4];
#pragma unroll
            for (int i = 0; i < 4; ++i) {
                const int r = wr + i * 16 + l15;
                af[i] = *(const bf16x8*)(Alds + r * 64 + ((kk * 4 + quad) ^ (r & 7)) * 8);
            }
#pragma unroll
            for (int j = 0; j < 4; ++j) {
                const int r = wc + j * 16 + l15;
                bfv[j] = *(const bf16x8*)(Blds + r * 64 + ((kk * 4 + quad) ^ (r & 7)) * 8);
            }
#pragma unroll
            for (int i = 0; i < 4; ++i)
#pragma unroll
                for (int j = 0; j < 4; ++j)
                    acc[i][j] = __builtin_amdgcn_mfma_f32_16x16x32_bf16(af[i], bfv[j], acc[i][j], 0, 0, 0);
        }
        if (has_next) {
            // Raw barrier: ds_reads already consumed, prefetch loads stay in flight.
            __builtin_amdgcn_sched_barrier(0);
            __builtin_amdgcn_s_barrier();
            __builtin_amdgcn_sched_barrier(0);
#pragma unroll
            for (int i = 0; i < 4; ++i) {
                const int flat = i * 256 + tid;
                *(bf16x8*)((char*)Alds + (long)flat * 16) = pfA[i];
                *(bf16x8*)((char*)Blds + (long)flat * 16) = regB ? scale8(pfB[i], zin) : pfB[i];
            }
        }
    }

    // Epilogue. C/D layout: col = lane&15, row = quad*4 + reg (verified m89/m91).
    if (mode >= 3) {
        float* C = (float*)Cvoid + zn * csn + zh * csh;
#pragma unroll
        for (int i = 0; i < 4; ++i)
#pragma unroll
            for (int j = 0; j < 4; ++j)
#pragma unroll
                for (int r = 0; r < 4; ++r) {
                    const long row = tM + wr + i * 16 + quad * 4 + r;
                    const long col = tN + wc + j * 16 + l15;
                    C[row * (long)ldc + col] = acc[i][j][r] + bias[row];
                }
    } else {
        bf16* Cb = (bf16*)Cvoid + zn * csn + zh * csh + tM * (long)ldc + tN;
        __syncthreads();
#pragma unroll
        for (int i = 0; i < 4; ++i)
#pragma unroll
            for (int j = 0; j < 4; ++j)
#pragma unroll
                for (int r = 0; r < 4; ++r) {
                    const int row = wr + i * 16 + quad * 4 + r;
                    const int col = wc + j * 16 + l15;
                    smem[row * 136 + col] = __float2bfloat16((acc[i][j][r] + bias[col]) * scale);
                }
        __syncthreads();
#pragma unroll
        for (int k = 0; k < 8; ++k) {
            const int fc  = k * 256 + tid;
            const int row = fc >> 4, cc = fc & 15;
            const f32x4 val = *(const f32x4*)((const char*)smem + row * 272 + cc * 16);
            *(f32x4*)((char*)(Cb + (long)row * ldc) + cc * 16) = val;
        }
    }
}

// ---------------------------------------------------------------------------
// Fused attention: per block (m-tile 64, nh). Streams Q l-tiles (128):
//   S^T[l,m] = q_l . k_m  (MFMA, A=Q B=K)  -> exp -> P[m][l] in LDS (b64 writes,
//   XOR-chunk layout = proven 0-conflict A-operand pattern) -> O[m,d] += P . V^T.
// Z[nh] accumulated via atomicAdd. out_tt written UNNORMALIZED (g4 divides by Z).
__global__ __launch_bounds__(256, 3)
void attn_fused(const bf16* __restrict__ scaled_t, const bf16* __restrict__ v2,
                bf16* __restrict__ out_tt, float* __restrict__ Z)
{
    __shared__ __align__(16) bf16 smem[20480];        // 40960 B
    bf16* SA = smem;                                   // K-chunk 64x64   [0,4096)
    bf16* SB = smem + 4096;                            // Q-chunk 128x64  [4096,12288)
    bf16* P  = smem + 12288;                           // P 64m x 128l    [12288,20480)
    // V-stage overlays [0,9216) (256d x 36); C-stage overlays [0,17408) in epilogue.

    const int tid  = threadIdx.x;
    const int wave = tid >> 6, lane = tid & 63;
    const int l15  = lane & 15, quad = lane >> 4;

    const int mt = blockIdx.x;                         // 16 m-tiles of 64
    const int by = blockIdx.y;                         // nh (64)
    const int n  = by >> 3, h = by & 7;
    const long m0 = (long)mt * 64;

    const bf16* Qb = scaled_t + (long)n * 6291456 + h * 768;
    const bf16* Kb = Qb + 256;
    const bf16* Vb = v2 + (long)by * 262144;

    const int wl  = wave >> 1, wm = wave & 1;          // S: wave tile 64l x 32m
    const int mOw = (wave >> 1) * 32, dOw = (wave & 1) * 128;  // O: 32m x 128d

    f32x4 accO[2][8] = {};
    float zsum = 0.0f;

    for (int lt = 0; lt < 8; ++lt) {
        const long l0 = (long)lt * 128;
        f32x4 accS[4][2] = {};
#pragma unroll 1
        for (int ks = 0; ks < 4; ++ks) {
            const long kof = (long)ks * 64;
#pragma unroll
            for (int i = 0; i < 2; ++i) {              // K-chunk 64 rows
                const int flat = i * 256 + tid;
                const int row  = flat >> 3;
                const int kcs  = (flat & 7) ^ (row & 7);
                async_copy16(Kb + (m0 + row) * 6144 + kof + kcs * 8,
                             (char*)SA + (long)(i * 256 + wave * 64) * 16);
            }
#pragma unroll
            for (int i = 0; i < 4; ++i) {              // Q-chunk 128 rows
                const int flat = i * 256 + tid;
                const int row  = flat >> 3;
                const int kcs  = (flat & 7) ^ (row & 7);
                async_copy16(Qb + (l0 + row) * 6144 + kof + kcs * 8,
                             (char*)SB + (long)(i * 256 + wave * 64) * 16);
            }
            __syncthreads();
#pragma unroll
            for (int kk = 0; kk < 2; ++kk) {
                bf16x8 af[4], bfv[2];
#pragma unroll
                for (int i = 0; i < 4; ++i) {
                    const int r = wl * 64 + i * 16 + l15;
                    af[i] = *(const bf16x8*)(SB + r * 64 + ((kk * 4 + quad) ^ (r & 7)) * 8);
                }
#pragma unroll
                for (int j = 0; j < 2; ++j) {
                    const int r = wm * 32 + j * 16 + l15;
                    bfv[j] = *(const bf16x8*)(SA + r * 64 + ((kk * 4 + quad) ^ (r & 7)) * 8);
                }
#pragma unroll
                for (int i = 0; i < 4; ++i)
#pragma unroll
                    for (int j = 0; j < 2; ++j)
                        accS[i][j] = __builtin_amdgcn_mfma_f32_16x16x32_bf16(af[i], bfv[j], accS[i][j], 0, 0, 0);
            }
            __syncthreads();
        }
        // exp -> P[m][l]; C-layout rows are l here (S^T), so 4 contig l pack to b64.
#pragma unroll
        for (int i = 0; i < 4; ++i)
#pragma unroll
            for (int j = 0; j < 2; ++j) {
                const int lrow = wl * 64 + i * 16 + quad * 4;
                const int m    = wm * 32 + j * 16 + l15;
                float e0 = __expf(accS[i][j][0]);
                float e1 = __expf(accS[i][j][1]);
                float e2 = __expf(accS[i][j][2]);
                float e3 = __expf(accS[i][j][3]);
                zsum += (e0 + e1) + (e2 + e3);
                bf16x4 pk;
                pk[0] = (__bf16)e0; pk[1] = (__bf16)e1; pk[2] = (__bf16)e2; pk[3] = (__bf16)e3;
                const int slot = (lrow >> 3) ^ (m & 7);
                *(bf16x4*)(P + m * 128 + slot * 8 + (lrow & 7)) = pk;
            }
        __syncthreads();
        // O-phase: 4 steps of 32 l; V staged padded (stride 36) via register writes.
#pragma unroll 1
        for (int os = 0; os < 4; ++os) {
#pragma unroll
            for (int c = 0; c < 4; ++c) {
                const int flat = c * 256 + tid;
                const int d = flat >> 2, cc = flat & 3;
                bf16x8 v = *(const bf16x8*)(Vb + (long)d * 1024 + l0 + os * 32 + cc * 8);
                *(bf16x8*)(smem + d * 36 + cc * 8) = v;
            }
            __syncthreads();
            bf16x8 af[2], bfv[8];
#pragma unroll
            for (int i = 0; i < 2; ++i) {
                const int m = mOw + i * 16 + l15;
                af[i] = *(const bf16x8*)(P + m * 128 + ((os * 4 + quad) ^ (m & 7)) * 8);
            }
#pragma unroll
            for (int j = 0; j < 8; ++j) {
                const int d = dOw + j * 16 + l15;
                bfv[j] = *(const bf16x8*)(smem + d * 36 + quad * 8);
            }
#pragma unroll
            for (int i = 0; i < 2; ++i)
#pragma unroll
                for (int j = 0; j < 8; ++j)
                    accO[i][j] = __builtin_amdgcn_mfma_f32_16x16x32_bf16(af[i], bfv[j], accO[i][j], 0, 0, 0);
            __syncthreads();
        }
    }

    // Z reduce: wave shuffle -> LDS (outside C-stage region) -> one atomicAdd.
#pragma unroll
    for (int o = 32; o > 0; o >>= 1) zsum += __shfl_down(zsum, o);
    float* Zs = (float*)(smem + 18432);
    if (lane == 0) Zs[wave] = zsum;
    __syncthreads();
    if (tid == 0) atomicAdd(Z + by, (Zs[0] + Zs[1]) + (Zs[2] + Zs[3]));

    // Epilogue: two d-halves through a 64x136 LDS stage, b128 coalesced stores.
    bf16* Ob = out_tt + (long)n * 2097152 + m0 * 2048 + h * 256;
    for (int hf = 0; hf < 2; ++hf) {
        if ((wave & 1) == hf) {
#pragma unroll
            for (int i = 0; i < 2; ++i)
#pragma unroll
                for (int j = 0; j < 8; ++j)
#pragma unroll
                    for (int r = 0; r < 4; ++r) {
                        const int row = mOw + i * 16 + quad * 4 + r;
                        const int col = j * 16 + l15;
                        smem[row * 136 + col] = __float2bfloat16(accO[i][j][r]);
                    }
        }
        __syncthreads();
#pragma unroll
        for (int k = 0; k < 4; ++k) {
            const int fc  = k * 256 + tid;
            const int row = fc >> 4, cc = fc & 15;
            const f32x4 val = *(const f32x4*)((const char*)smem + row * 272 + cc * 16);
            *(f32x4*)((char*)(Ob + (long)row * 2048 + hf * 128) + cc * 16) = val;
        }
        __syncthreads();
    }
}

// ---------------------------------------------------------------------------
// Convert weights to bf16; zero the Z accumulator (ws is poisoned each call).
__global__ void prep_convert(const float* __restrict__ w_in, const float* __restrict__ w_out,
                             bf16* __restrict__ w_in_b, bf16* __restrict__ w_out_b,
                             float* __restrict__ Z)
{
    const long gid = (long)blockIdx.x * 256 + threadIdx.x;
    if (blockIdx.x == 0 && threadIdx.x < 64) Z[threadIdx.x] = 0.0f;
    const long n1 = 6144L * 256;
    const long n2 = 256L * 2048;
    const long stride = (long)gridDim.x * 256;
    for (long i = gid; i < n1; i += stride) w_in_b[i] = __float2bfloat16(w_in[i]);
    for (long i = gid; i < n2; i += stride) w_out_b[i] = __float2bfloat16(w_out[i]);
}

// x (n, 256 c, 1024 l) f32 -> x_t (n, 1024 l, 256 c) bf16, 64x64 LDS tiles.
__global__ void prep_xt(const float* __restrict__ x, bf16* __restrict__ x_t)
{
    __shared__ float tile[64][65];
    const int b = blockIdx.x;
    const int n = blockIdx.y;
    const int ct = b & 3, lt = b >> 2;
    const int t = threadIdx.x;
    const float* xp = x + (long)n * 256 * 1024;
#pragma unroll
    for (int i = 0; i < 16; ++i) {
        const int flat = i * 256 + t;
        const int cl = flat >> 6, ll = flat & 63;
        tile[cl][ll] = xp[(long)(ct * 64 + cl) * 1024 + lt * 64 + ll];
    }
    __syncthreads();
    bf16* xo = x_t + (long)n * 1024 * 256;
#pragma unroll
    for (int i = 0; i < 16; ++i) {
        const int flat = i * 256 + t;
        const int lr = flat >> 6, cr = flat & 63;
        xo[(long)(lt * 64 + lr) * 256 + ct * 64 + cr] = __float2bfloat16(tile[cr][lr]);
    }
}

// v2[n,h,d,l] = scaled_t[n,l,h*768+512+d]  (bf16 -> bf16 tiled transpose)
__global__ void prep_v2(const bf16* __restrict__ scaled_t, bf16* __restrict__ v2)
{
    __shared__ bf16 tile[64][74];
    const int b  = blockIdx.x;
    const int nh = blockIdx.y;
    const int dt = b & 3, lt = b >> 2;
    const int n = nh >> 3, h = nh & 7;
    const int t = threadIdx.x;
    const bf16* sp = scaled_t + (long)n * 1024 * 6144 + h * 768 + 512;
#pragma unroll
    for (int i = 0; i < 16; ++i) {
        const int flat = i * 256 + t;
        const int lr = flat >> 6, dc = flat & 63;
        tile[dc][lr] = sp[(long)(lt * 64 + lr) * 6144 + dt * 64 + dc];
    }
    __syncthreads();
    bf16* vp = v2 + ((long)nh * 256 + dt * 64) * 1024;
#pragma unroll
    for (int i = 0; i < 16; ++i) {
        const int flat = i * 256 + t;
        const int dr = flat >> 6, lc = flat & 63;
        vp[(long)dr * 1024 + lt * 64 + lc] = tile[dr][lc];
    }
}

extern "C" void kernel_launch(void* const* d_in, const int* in_sizes, int n_in,
                              void* d_out, int out_size, void* d_ws, size_t ws_size,
                              hipStream_t stream)
{
    const float* x     = (const float*)d_in[0];
    const float* w_in  = (const float*)d_in[1];
    const float* b_in  = (const float*)d_in[2];
    const float* w_out = (const float*)d_in[3];
    const float* b_out = (const float*)d_in[4];
    float* out = (float*)d_out;

    const float SCALE = 0.10416666666666667f;     // 1/16 * sqrt(6400/2304) = 5/48

    char* p = (char*)d_ws;
    bf16* scaled_t = (bf16*)p;  p += 100663296;   // (8, 1024, 6144) bf16
    bf16* v2       = (bf16*)p;  p += 33554432;    // (8, 8, 256, 1024) bf16
    bf16* out_tt   = (bf16*)p;  p += 33554432;    // (8, 1024, 2048) bf16 (unnormalized)
    bf16* x_t      = (bf16*)p;  p += 4194304;     // (8, 1024, 256) bf16
    bf16* w_in_b   = (bf16*)p;  p += 3145728;     // (6144, 256) bf16
    bf16* w_out_b  = (bf16*)p;  p += 1048576;     // (256, 2048) bf16
    float* Z       = (float*)p; p += 256;         // 64 softmax denominators

    prep_convert<<<2048, 256, 0, stream>>>(w_in, w_out, w_in_b, w_out_b, Z);
    prep_xt<<<dim3(64, 8), 256, 0, stream>>>(x, x_t);

    // g1: scaled_t[n,l,o], M=1024(l) N=6144(o) K=256(c)
    gemm_nt<<<dim3(48, 8, 8), 256, 0, stream>>>(
        x_t, w_in_b, scaled_t,
        1024, 6144, 256, 256, 256, 6144,
        1024L * 256, 0, 0, 0, 1024L * 6144, 0,
        1, 0, b_in, nullptr, SCALE);

    prep_v2<<<dim3(64, 64), 256, 0, stream>>>(scaled_t, v2);

    // fused attention: replaces g2 + g3 + the 134 MB Pbuf round-trip
    attn_fused<<<dim3(16, 64), 256, 0, stream>>>(scaled_t, v2, out_tt, Z);

    // g4: out[n,c,m] = w_out . (out_tt/Z) + b_out, M=256(c) N=1024(m) K=2048(a)
    gemm_nt<<<dim3(8, 2, 8), 256, 0, stream>>>(
        w_out_b, out_tt, out,
        256, 1024, 2048, 2048, 2048, 1024,
        0, 0, 1024L * 2048, 0, 256L * 1024, 0,
        1, 4, b_out, Z, 1.0f);
}

// Round 6
// 262.034 us; speedup vs baseline: 2.4197x; 1.2472x over previous
//
#include <hip/hip_runtime.h>
#include <hip/hip_bf16.h>

// MultiHeadAttention: x(8,256,32,32) -> qkv proj -> global-softmax attention -> out proj.
//   g1 (gemm_nt mode 0): scaled_t[n,l,o] = (x_t . w_in + b_in) * SCALE       (K=256)
//   attn_fused:          out_tt[n,m,h*256+d] = Sum_l exp(q_l.k_m) v[d,l]  (UNNORMALIZED)
//                        Z[nh] = Sum exp(q.k)
//   g4 (gemm_nt mode 4): out[n,c,m] = w_out . (out_tt/Z) + b_out
// Global softmax: att ~ N(0,0.17^2) -> exp() without max-subtraction is safe.
// R6: attn_fused rewritten: XCD-affinity block swizzle (16 same-nh blocks -> one XCD L2),
//     K-tile resident in LDS, l-tile=64 with Q/V overlay, register-prefetch + raw barriers
//     (4 barriers per l-tile instead of 16, all drains overlapped).

typedef __bf16 bf16x8 __attribute__((ext_vector_type(8)));
typedef __bf16 bf16x4 __attribute__((ext_vector_type(4)));
typedef float f32x4 __attribute__((ext_vector_type(4)));
typedef __hip_bfloat16 bf16;

__device__ __forceinline__ void async_copy16(const void* g, void* s) {
    __builtin_amdgcn_global_load_lds(
        (const __attribute__((address_space(1))) unsigned int*)g,
        (__attribute__((address_space(3))) unsigned int*)s, 16, 0, 0);
}

__device__ __forceinline__ bf16x8 scale8(bf16x8 v, float s) {
    bf16x8 r;
#pragma unroll
    for (int e = 0; e < 8; ++e) r[e] = (__bf16)((float)v[e] * s);
    return r;
}

// ---------------------------------------------------------------------------
// Generic NT bf16 GEMM, 128x128 tile, BK=64, 256 threads (2x2 waves).
// Register-prefetch pipelined K-loop (R4), XOR-swizzled LDS (R3, 0 conflicts).
// mode 0: C=bf16, (acc + bias[col]) * scale
// mode 3: C=f32,  acc + bias[row]
// mode 4: C=f32,  acc + bias[row]; B scaled by 1/Zp[zn*8 + k/256] during staging
__global__ __launch_bounds__(256)
void gemm_nt(const bf16* __restrict__ A, const bf16* __restrict__ B, void* __restrict__ Cvoid,
             int M, int N, int K, int lda, int ldb, int ldc,
             long asn, long ash, long bsn, long bsh, long csn, long csh,
             int H, int mode, const float* __restrict__ bias, const float* __restrict__ Zp,
             float scale)
{
    __shared__ __align__(16) bf16 smem[17408];
    bf16* Alds = smem;
    bf16* Blds = smem + 8192;

    const int tid  = threadIdx.x;
    const int wave = tid >> 6;
    const int lane = tid & 63;
    const int z  = blockIdx.z;
    const int zn = z / H, zh = z % H;

    const bf16* Ab = A + zn * asn + zh * ash;
    const bf16* Bb = B + zn * bsn + zh * bsh;

    const long tM = (long)blockIdx.y * 128;
    const long tN = (long)blockIdx.x * 128;

    const int wr   = (wave >> 1) * 64;
    const int wc   = (wave & 1) * 64;
    const int l15  = lane & 15;
    const int quad = lane >> 4;

    f32x4 acc[4][4] = {};

    const int kiters = K >> 6;
    const bool regB = (mode == 4);

#pragma unroll
    for (int i = 0; i < 4; ++i) {
        const int flat = i * 256 + tid;
        const int row  = flat >> 3;
        const int kcs  = (flat & 7) ^ (row & 7);
        async_copy16(Ab + (tM + row) * (long)lda + kcs * 8,
                     (char*)Alds + (long)(i * 256 + wave * 64) * 16);
        if (!regB) {
            async_copy16(Bb + (tN + row) * (long)ldb + kcs * 8,
                         (char*)Blds + (long)(i * 256 + wave * 64) * 16);
        }
    }
    if (regB) {
        const float zi0 = 1.0f / Zp[zn * 8];
#pragma unroll
        for (int i = 0; i < 4; ++i) {
            const int flat = i * 256 + tid;
            const int row  = flat >> 3;
            const int kcs  = (flat & 7) ^ (row & 7);
            bf16x8 b = *(const bf16x8*)(Bb + (tN + row) * (long)ldb + kcs * 8);
            *(bf16x8*)((char*)Blds + (long)flat * 16) = scale8(b, zi0);
        }
    }

    bf16x8 pfA[4], pfB[4];
    for (int kt = 0; kt < kiters; ++kt) {
        __syncthreads();
        const bool has_next = (kt + 1 < kiters);
        float zin = 1.0f;
        if (has_next) {
            const long kof = (long)(kt + 1) * 64;
            if (regB) zin = 1.0f / Zp[zn * 8 + ((kt + 1) >> 2)];
#pragma unroll
            for (int i = 0; i < 4; ++i) {
                const int flat = i * 256 + tid;
                const int row  = flat >> 3;
                const int kcs  = (flat & 7) ^ (row & 7);
                pfA[i] = *(const bf16x8*)(Ab + (tM + row) * (long)lda + kof + kcs * 8);
                pfB[i] = *(const bf16x8*)(Bb + (tN + row) * (long)ldb + kof + kcs * 8);
            }
        }
#pragma unroll
        for (int kk = 0; kk < 2; ++kk) {
            bf16x8 af[4], bfv[4];
#pragma unroll
            for (int i = 0; i < 4; ++i) {
                const int r = wr + i * 16 + l15;
                af[i] = *(const bf16x8*)(Alds + r * 64 + ((kk * 4 + quad) ^ (r & 7)) * 8);
            }
#pragma unroll
            for (int j = 0; j < 4; ++j) {
                const int r = wc + j * 16 + l15;
                bfv[j] = *(const bf16x8*)(Blds + r * 64 + ((kk * 4 + quad) ^ (r & 7)) * 8);
            }
#pragma unroll
            for (int i = 0; i < 4; ++i)
#pragma unroll
                for (int j = 0; j < 4; ++j)
                    acc[i][j] = __builtin_amdgcn_mfma_f32_16x16x32_bf16(af[i], bfv[j], acc[i][j], 0, 0, 0);
        }
        if (has_next) {
            __builtin_amdgcn_sched_barrier(0);
            __builtin_amdgcn_s_barrier();
            __builtin_amdgcn_sched_barrier(0);
#pragma unroll
            for (int i = 0; i < 4; ++i) {
                const int flat = i * 256 + tid;
                *(bf16x8*)((char*)Alds + (long)flat * 16) = pfA[i];
                *(bf16x8*)((char*)Blds + (long)flat * 16) = regB ? scale8(pfB[i], zin) : pfB[i];
            }
        }
    }

    if (mode >= 3) {
        float* C = (float*)Cvoid + zn * csn + zh * csh;
#pragma unroll
        for (int i = 0; i < 4; ++i)
#pragma unroll
            for (int j = 0; j < 4; ++j)
#pragma unroll
                for (int r = 0; r < 4; ++r) {
                    const long row = tM + wr + i * 16 + quad * 4 + r;
                    const long col = tN + wc + j * 16 + l15;
                    C[row * (long)ldc + col] = acc[i][j][r] + bias[row];
                }
    } else {
        bf16* Cb = (bf16*)Cvoid + zn * csn + zh * csh + tM * (long)ldc + tN;
        __syncthreads();
#pragma unroll
        for (int i = 0; i < 4; ++i)
#pragma unroll
            for (int j = 0; j < 4; ++j)
#pragma unroll
                for (int r = 0; r < 4; ++r) {
                    const int row = wr + i * 16 + quad * 4 + r;
                    const int col = wc + j * 16 + l15;
                    smem[row * 136 + col] = __float2bfloat16((acc[i][j][r] + bias[col]) * scale);
                }
        __syncthreads();
#pragma unroll
        for (int k = 0; k < 8; ++k) {
            const int fc  = k * 256 + tid;
            const int row = fc >> 4, cc = fc & 15;
            const f32x4 val = *(const f32x4*)((const char*)smem + row * 272 + cc * 16);
            *(f32x4*)((char*)(Cb + (long)row * ldc) + cc * 16) = val;
        }
    }
}

// ---------------------------------------------------------------------------
// Fused attention v2. Block = (m-tile of 64 keys, nh), 1D grid with XCD swizzle.
// K-tile (64x256, 32KB) resident in LDS. Per l-tile (64 q-rows):
//   [Q in LDS from prefetch] issue V->regs; S = Q.K^T (8 MFMA windows, no barriers);
//   exp -> P[m][l] LDS; raw barrier; ds_write V (overlays Q); syncthreads (vmem empty);
//   issue Qnext->regs; O += P.V^T; raw barrier; ds_write Qnext; syncthreads.
// All LDS tiles XOR-chunk swizzled: slot = (c&24)|((c&7)^(row&7)) -> 2-way max (free).
__global__ __launch_bounds__(256, 2)
void attn_fused(const bf16* __restrict__ scaled_t, const bf16* __restrict__ v2,
                bf16* __restrict__ out_tt, float* __restrict__ Z)
{
    __shared__ __align__(16) bf16 smem[36880];
    bf16* Ks = smem;            // 64m x 256d   [0, 16384)
    bf16* Qs = smem + 16384;    // 64l x 256d   [16384, 32768)  (V 256d x 64l overlays)
    bf16* Ps = smem + 32768;    // 64m x 64l    [32768, 36864)
    float* Zs = (float*)(smem + 36864);

    const int tid  = threadIdx.x;
    const int wave = tid >> 6, lane = tid & 63;
    const int l15  = lane & 15, quad = lane >> 4;

    // XCD-affinity swizzle: blocks with id = same (mod 8) share an XCD (round-robin
    // heuristic). nh = xcd*8 + (s>>4) puts all 16 m-tiles of one (n,h) on one XCD.
    const int b   = blockIdx.x;
    const int xcd = b & 7, s = b >> 3;
    const int nh  = xcd * 8 + (s >> 4);
    const int mt  = s & 15;
    const int n   = nh >> 3, h = nh & 7;
    const long m0 = (long)mt * 64;

    const bf16* Qb = scaled_t + (long)n * 6291456 + h * 768;
    const bf16* Kb = Qb + 256;
    const bf16* Vb = v2 + (long)nh * 262144;

    f32x4 accO[16] = {};
    float zsum = 0.0f;

    // Prologue: K-tile via async glds; Q l-tile 0 via regs.
#pragma unroll
    for (int i = 0; i < 8; ++i) {
        const int flat = i * 256 + tid;
        const int row  = flat >> 5;
        const int ch   = flat & 31;
        const int kcs  = (ch & 24) | ((ch & 7) ^ (row & 7));
        async_copy16(Kb + (m0 + row) * 6144 + kcs * 8,
                     (char*)Ks + (long)(i * 256 + wave * 64) * 16);
    }
    {
        bf16x8 q0[8];
#pragma unroll
        for (int i = 0; i < 8; ++i) {
            const int flat = i * 256 + tid;
            const int row  = flat >> 5;
            const int ch   = flat & 31;
            const int kcs  = (ch & 24) | ((ch & 7) ^ (row & 7));
            q0[i] = *(const bf16x8*)(Qb + (long)row * 6144 + kcs * 8);
        }
#pragma unroll
        for (int i = 0; i < 8; ++i)
            *(bf16x8*)((char*)Qs + (long)(i * 256 + tid) * 16) = q0[i];
    }
    __syncthreads();

    bf16x8 pfV[8], pfQ[8];
    for (int lt = 0; lt < 16; ++lt) {
        const long l0 = (long)lt * 64;

        // Issue V loads (consumed after the raw barrier; overlap S-compute).
#pragma unroll
        for (int i = 0; i < 8; ++i) {
            const int flat = i * 256 + tid;
            const int d    = flat >> 3;
            const int kcs  = (flat & 7) ^ (d & 7);
            pfV[i] = *(const bf16x8*)(Vb + (long)d * 1024 + l0 + kcs * 8);
        }

        // S-phase: D[l(16/wave), m(64)] over 8 K-windows, all operands LDS-resident.
        f32x4 accS[4] = {};
        const int qrow = wave * 16 + l15;
#pragma unroll
        for (int w = 0; w < 8; ++w) {
            const int cw = w * 4 + quad;
            const bf16x8 af = *(const bf16x8*)(
                Qs + qrow * 256 + ((cw & 24) | ((cw & 7) ^ (qrow & 7))) * 8);
#pragma unroll
            for (int j = 0; j < 4; ++j) {
                const int krow = j * 16 + l15;
                const bf16x8 bfv = *(const bf16x8*)(
                    Ks + krow * 256 + ((cw & 24) | ((cw & 7) ^ (krow & 7))) * 8);
                accS[j] = __builtin_amdgcn_mfma_f32_16x16x32_bf16(af, bfv, accS[j], 0, 0, 0);
            }
        }
        // exp -> P[m][l]. C-layout: row(l) = quad*4+r, col(m) = l15.
        {
            const int lbase = wave * 16 + quad * 4;
            const int chunk = lbase >> 3;
#pragma unroll
            for (int j = 0; j < 4; ++j) {
                const int m = j * 16 + l15;
                float e0 = __expf(accS[j][0]);
                float e1 = __expf(accS[j][1]);
                float e2 = __expf(accS[j][2]);
                float e3 = __expf(accS[j][3]);
                zsum += (e0 + e1) + (e2 + e3);
                bf16x4 pk;
                pk[0] = (__bf16)e0; pk[1] = (__bf16)e1; pk[2] = (__bf16)e2; pk[3] = (__bf16)e3;
                *(bf16x4*)(Ps + m * 64 + (chunk ^ (m & 7)) * 8 + (lbase & 7)) = pk;
            }
        }
        // Raw barrier: Q reads + P writes done wave-locally; V loads stay in flight.
        __builtin_amdgcn_sched_barrier(0);
        __builtin_amdgcn_s_barrier();
        __builtin_amdgcn_sched_barrier(0);
#pragma unroll
        for (int i = 0; i < 8; ++i)
            *(bf16x8*)((char*)Qs + (long)(i * 256 + tid) * 16) = pfV[i];  // V overlays Q
        __syncthreads();  // lgkm drain; vmem queue empty (pfV consumed) -> cheap

        // Issue next Q loads (overlap O-compute).
        if (lt < 15) {
            const long l0n = l0 + 64;
#pragma unroll
            for (int i = 0; i < 8; ++i) {
                const int flat = i * 256 + tid;
                const int row  = flat >> 5;
                const int ch   = flat & 31;
                const int kcs  = (ch & 24) | ((ch & 7) ^ (row & 7));
                pfQ[i] = *(const bf16x8*)(Qb + (l0n + row) * 6144 + kcs * 8);
            }
        }

        // O-phase: O[m(16/wave), d(256)] += P . V^T, K=64 (2 windows).
        const int mrow = wave * 16 + l15;
#pragma unroll
        for (int w = 0; w < 2; ++w) {
            const int cw = w * 4 + quad;
            const bf16x8 af = *(const bf16x8*)(Ps + mrow * 64 + (cw ^ (mrow & 7)) * 8);
#pragma unroll
            for (int j = 0; j < 16; ++j) {
                const int d = j * 16 + l15;
                const bf16x8 bfv = *(const bf16x8*)(Qs + d * 64 + (cw ^ (d & 7)) * 8);
                accO[j] = __builtin_amdgcn_mfma_f32_16x16x32_bf16(af, bfv, accO[j], 0, 0, 0);
            }
        }
        __builtin_amdgcn_sched_barrier(0);
        __builtin_amdgcn_s_barrier();
        __builtin_amdgcn_sched_barrier(0);
        if (lt < 15) {
#pragma unroll
            for (int i = 0; i < 8; ++i)
                *(bf16x8*)((char*)Qs + (long)(i * 256 + tid) * 16) = pfQ[i];
        }
        __syncthreads();
    }

    // Z reduction: wave shuffle -> LDS -> one atomicAdd per block.
#pragma unroll
    for (int o = 32; o > 0; o >>= 1) zsum += __shfl_down(zsum, o);
    if (lane == 0) Zs[wave] = zsum;
    __syncthreads();
    if (tid == 0) atomicAdd(Z + nh, (Zs[0] + Zs[1]) + (Zs[2] + Zs[3]));

    // Epilogue: stage 64m x 256d through LDS (stride 264), b128 coalesced stores.
    bf16* Cs = smem + 16384;
#pragma unroll
    for (int j = 0; j < 16; ++j)
#pragma unroll
        for (int r = 0; r < 4; ++r) {
            const int row = wave * 16 + quad * 4 + r;
            const int col = j * 16 + l15;
            Cs[row * 264 + col] = __float2bfloat16(accO[j][r]);
        }
    __syncthreads();
    bf16* Ob = out_tt + (long)n * 2097152 + m0 * 2048 + h * 256;
#pragma unroll
    for (int k = 0; k < 8; ++k) {
        const int flat = k * 256 + tid;
        const int row  = flat >> 5;
        const int cc   = flat & 31;
        const f32x4 val = *(const f32x4*)((const char*)Cs + (row * 264 + cc * 8) * 2);
        *(f32x4*)((char*)(Ob + (long)row * 2048) + cc * 16) = val;
    }
}

// ---------------------------------------------------------------------------
__global__ void prep_convert(const float* __restrict__ w_in, const float* __restrict__ w_out,
                             bf16* __restrict__ w_in_b, bf16* __restrict__ w_out_b,
                             float* __restrict__ Z)
{
    const long gid = (long)blockIdx.x * 256 + threadIdx.x;
    if (blockIdx.x == 0 && threadIdx.x < 64) Z[threadIdx.x] = 0.0f;
    const long n1 = 6144L * 256;
    const long n2 = 256L * 2048;
    const long stride = (long)gridDim.x * 256;
    for (long i = gid; i < n1; i += stride) w_in_b[i] = __float2bfloat16(w_in[i]);
    for (long i = gid; i < n2; i += stride) w_out_b[i] = __float2bfloat16(w_out[i]);
}

__global__ void prep_xt(const float* __restrict__ x, bf16* __restrict__ x_t)
{
    __shared__ float tile[64][65];
    const int b = blockIdx.x;
    const int n = blockIdx.y;
    const int ct = b & 3, lt = b >> 2;
    const int t = threadIdx.x;
    const float* xp = x + (long)n * 256 * 1024;
#pragma unroll
    for (int i = 0; i < 16; ++i) {
        const int flat = i * 256 + t;
        const int cl = flat >> 6, ll = flat & 63;
        tile[cl][ll] = xp[(long)(ct * 64 + cl) * 1024 + lt * 64 + ll];
    }
    __syncthreads();
    bf16* xo = x_t + (long)n * 1024 * 256;
#pragma unroll
    for (int i = 0; i < 16; ++i) {
        const int flat = i * 256 + t;
        const int lr = flat >> 6, cr = flat & 63;
        xo[(long)(lt * 64 + lr) * 256 + ct * 64 + cr] = __float2bfloat16(tile[cr][lr]);
    }
}

__global__ void prep_v2(const bf16* __restrict__ scaled_t, bf16* __restrict__ v2)
{
    __shared__ bf16 tile[64][74];
    const int b  = blockIdx.x;
    const int nh = blockIdx.y;
    const int dt = b & 3, lt = b >> 2;
    const int n = nh >> 3, h = nh & 7;
    const int t = threadIdx.x;
    const bf16* sp = scaled_t + (long)n * 1024 * 6144 + h * 768 + 512;
#pragma unroll
    for (int i = 0; i < 16; ++i) {
        const int flat = i * 256 + t;
        const int lr = flat >> 6, dc = flat & 63;
        tile[dc][lr] = sp[(long)(lt * 64 + lr) * 6144 + dt * 64 + dc];
    }
    __syncthreads();
    bf16* vp = v2 + ((long)nh * 256 + dt * 64) * 1024;
#pragma unroll
    for (int i = 0; i < 16; ++i) {
        const int flat = i * 256 + t;
        const int dr = flat >> 6, lc = flat & 63;
        vp[(long)dr * 1024 + lt * 64 + lc] = tile[dr][lc];
    }
}

extern "C" void kernel_launch(void* const* d_in, const int* in_sizes, int n_in,
                              void* d_out, int out_size, void* d_ws, size_t ws_size,
                              hipStream_t stream)
{
    const float* x     = (const float*)d_in[0];
    const float* w_in  = (const float*)d_in[1];
    const float* b_in  = (const float*)d_in[2];
    const float* w_out = (const float*)d_in[3];
    const float* b_out = (const float*)d_in[4];
    float* out = (float*)d_out;

    const float SCALE = 0.10416666666666667f;     // 1/16 * sqrt(6400/2304) = 5/48

    char* p = (char*)d_ws;
    bf16* scaled_t = (bf16*)p;  p += 100663296;   // (8, 1024, 6144) bf16
    bf16* v2       = (bf16*)p;  p += 33554432;    // (8, 8, 256, 1024) bf16
    bf16* out_tt   = (bf16*)p;  p += 33554432;    // (8, 1024, 2048) bf16 (unnormalized)
    bf16* x_t      = (bf16*)p;  p += 4194304;     // (8, 1024, 256) bf16
    bf16* w_in_b   = (bf16*)p;  p += 3145728;     // (6144, 256) bf16
    bf16* w_out_b  = (bf16*)p;  p += 1048576;     // (256, 2048) bf16
    float* Z       = (float*)p; p += 256;         // 64 softmax denominators

    prep_convert<<<2048, 256, 0, stream>>>(w_in, w_out, w_in_b, w_out_b, Z);
    prep_xt<<<dim3(64, 8), 256, 0, stream>>>(x, x_t);

    // g1: scaled_t[n,l,o], M=1024(l) N=6144(o) K=256(c)
    gemm_nt<<<dim3(48, 8, 8), 256, 0, stream>>>(
        x_t, w_in_b, scaled_t,
        1024, 6144, 256, 256, 256, 6144,
        1024L * 256, 0, 0, 0, 1024L * 6144, 0,
        1, 0, b_in, nullptr, SCALE);

    prep_v2<<<dim3(64, 64), 256, 0, stream>>>(scaled_t, v2);

    // fused attention (1D grid, XCD-swizzled)
    attn_fused<<<1024, 256, 0, stream>>>(scaled_t, v2, out_tt, Z);

    // g4: out[n,c,m] = w_out . (out_tt/Z) + b_out, M=256(c) N=1024(m) K=2048(a)
    gemm_nt<<<dim3(8, 2, 8), 256, 0, stream>>>(
        w_out_b, out_tt, out,
        256, 1024, 2048, 2048, 2048, 1024,
        0, 0, 1024L * 2048, 0, 256L * 1024, 0,
        1, 4, b_out, Z, 1.0f);
}